// Round 10
// baseline (229.161 us; speedup 1.0000x reference)
//
#include <hip/hip_runtime.h>
#include <math.h>

// Problem constants
#define NP 8836          // number of patches per image (94*94)
#define PW 94            // patches per row
#define IW 96            // image width/height
#define CH 256           // channels
#define NTILE 70         // ceil(8836/128)  (fallback GEMM)
#define KT2 18           // fallback K tiles
#define NWG (NTILE * NTILE)
#define NPIX 9216        // 96*96 pixels
#define GTS 9216         // GT row stride in elements

typedef int   i32x4  __attribute__((ext_vector_type(4)));
typedef int   i32x8  __attribute__((ext_vector_type(8)));
typedef float f32x16 __attribute__((ext_vector_type(16)));

__device__ __forceinline__ unsigned int ordf(float f) {
  unsigned int u = __float_as_uint(f);
  return (u & 0x80000000u) ? ~u : (u | 0x80000000u);
}

__device__ __forceinline__ float blo(unsigned int x) {   // low bf16 -> f32 (exact)
  return __uint_as_float(x << 16);
}
__device__ __forceinline__ float bhi(unsigned int x) {   // high bf16 -> f32 (exact)
  return __uint_as_float(x & 0xFFFF0000u);
}

typedef const __attribute__((address_space(1))) void GvoidC;
typedef __attribute__((address_space(3))) void Lvoid;
__device__ __forceinline__ void gl16(const void* g, void* l) {
  __builtin_amdgcn_global_load_lds((GvoidC*)g, (Lvoid*)l, 16, 0, 0);
}

// ---------------------------------------------------------------------------
// 1) Convert+transpose [C, 9216] fp32 -> [9216, C] fp8 (HW v_cvt encoding).
// ---------------------------------------------------------------------------
__global__ __launch_bounds__(256) void prep_kernel(
    const float* __restrict__ inA, const float* __restrict__ inB,
    unsigned int* __restrict__ TA, unsigned int* __restrict__ TB) {
  __shared__ float tile[64][65];
  int bid = blockIdx.x;            // [0, 1152)
  const float* src; unsigned int* dst;
  if (bid < 576) { src = inA; dst = TA; }
  else           { src = inB; dst = TB; bid -= 576; }
  int cT  = bid & 3;        // c-tile   [0,4)  (64 channels)
  int xyT = bid >> 2;       // xy-tile  [0,144)
  int t = threadIdx.x;
  int l = t & 63, h = t >> 6;

  #pragma unroll
  for (int i = 0; i < 16; ++i) {
    int c = h * 16 + i;
    tile[c][l] = src[(size_t)(cT * 64 + c) * (IW * IW) + xyT * 64 + l];
  }
  __syncthreads();
  int cu = t & 15;          // u32 column within the 64-channel tile
  #pragma unroll
  for (int i = 0; i < 4; ++i) {
    int xy = (t >> 4) + i * 16;
    int c = cu * 4;
    unsigned int v = __builtin_amdgcn_cvt_pk_fp8_f32(tile[c][xy],     tile[c + 1][xy], 0, false);
    v              = __builtin_amdgcn_cvt_pk_fp8_f32(tile[c + 2][xy], tile[c + 3][xy], v, true);
    dst[(size_t)(xyT * 64 + xy) * 64 + cT * 16 + cu] = v;
  }
}

// ---------------------------------------------------------------------------
// 2) Per-patch squared norms from the fp8 images (consistent with GEMM dtype).
// ---------------------------------------------------------------------------
__global__ void norms_kernel(const unsigned int* __restrict__ TA, const unsigned int* __restrict__ TB,
                             float* __restrict__ rnormS, float* __restrict__ normS,
                             float* __restrict__ normsqS, float* __restrict__ synsq) {
  int wid  = blockIdx.x * 4 + (threadIdx.x >> 6);
  int lane = threadIdx.x & 63;
  bool isStyle = wid < NP;
  int p = isStyle ? wid : wid - NP;
  if (p >= NP) return;
  const unsigned int* T = isStyle ? TB : TA;
  int pi = p / PW, pj = p % PW;
  float s = 0.f;
  #pragma unroll
  for (int kh = 0; kh < 3; ++kh) {
    #pragma unroll
    for (int kw = 0; kw < 3; ++kw) {
      unsigned int v = T[(size_t)((pi + kh) * IW + (pj + kw)) * 64 + lane];
      float f0 = __builtin_amdgcn_cvt_f32_fp8(v, 0);
      float f1 = __builtin_amdgcn_cvt_f32_fp8(v, 1);
      float f2 = __builtin_amdgcn_cvt_f32_fp8(v, 2);
      float f3 = __builtin_amdgcn_cvt_f32_fp8(v, 3);
      s += f0 * f0 + f1 * f1 + f2 * f2 + f3 * f3;
    }
  }
  #pragma unroll
  for (int m = 32; m >= 1; m >>= 1) s += __shfl_xor(s, m, 64);
  if (lane == 0) {
    if (isStyle) {
      normsqS[p] = s;
      float n = sqrtf(s);
      normS[p]  = n;
      rnormS[p] = 1.f / n;
    } else {
      synsq[p] = s;
    }
  }
}

__device__ __forceinline__ i32x8 ldfrag(const unsigned char* rowp, int o0, int o1) {
  i32x4 lo = *(const i32x4*)(rowp + o0);
  i32x4 hi = *(const i32x4*)(rowp + o1);
  return __builtin_shufflevector(lo, hi, 0, 1, 2, 3, 4, 5, 6, 7);
}

// ---------------------------------------------------------------------------
// 3a) G-path kernel 1: pixel Gram GT[y][x] = sum_ch TB[y][ch]*TA[x][ch],
//     M=N=9216, K=256 (2 BK=128 steps), 128x128 tiles (72x72 grid), bf16 out.
//     bf16 storage + all-f32 tap summation is the R6-PROVEN numerics.
// ---------------------------------------------------------------------------
__global__ __launch_bounds__(256, 2) void g_gemm_kernel(
    const unsigned char* __restrict__ TA, const unsigned char* __restrict__ TB,
    unsigned short* __restrict__ GT) {
  __shared__ unsigned char As[128 * 128];
  __shared__ unsigned char Bs[128 * 128];

  // XCD-chunked bijective swizzle: 5184 = 8*648.
  int orig = blockIdx.x;
  int pid = (orig & 7) * 648 + (orig >> 3);
  int yt = pid % 72, xt = pid / 72;     // per-XCD chunk = 9 xt panels:
  int y0 = yt * 128, x0 = xt * 128;     // TB(2.4MB)+9 TA panels fit 4MB L2.
  int t = threadIdx.x, lane = t & 63, wave = t >> 6;
  int wm = wave >> 1, wn = wave & 1;

  int rr = t >> 3;
  int qc = (t & 7) ^ (rr & 7);
  const unsigned char* gA[4];
  const unsigned char* gB[4];
  #pragma unroll
  for (int i = 0; i < 4; ++i) {
    gA[i] = TB + (size_t)(y0 + 32 * i + rr) * CH + qc * 16;   // A-op = style y
    gB[i] = TA + (size_t)(x0 + 32 * i + rr) * CH + qc * 16;   // B-op = synth x
  }
  unsigned char* lA = As + t * 16;
  unsigned char* lB = Bs + t * 16;

  f32x16 acc[2][2];
  #pragma unroll
  for (int mi = 0; mi < 2; ++mi)
    #pragma unroll
    for (int ni = 0; ni < 2; ++ni)
      #pragma unroll
      for (int j = 0; j < 16; ++j) acc[mi][ni][j] = 0.f;

  int kq = lane >> 5, sw = lane & 7;
  const unsigned char* Arow = As + (size_t)(wm * 64 + (lane & 31)) * 128;
  const unsigned char* Brow = Bs + (size_t)(wn * 64 + (lane & 31)) * 128;

  #pragma unroll 1
  for (int kt = 0; kt < 2; ++kt) {
    int choff = kt * 128;
    if (kt) __syncthreads();
    #pragma unroll
    for (int i = 0; i < 4; ++i) {
      gl16(gA[i] + choff, lA + i * 4096);
      gl16(gB[i] + choff, lB + i * 4096);
    }
    __syncthreads();
    #pragma unroll
    for (int h = 0; h < 2; ++h) {
      int c0 = 2 * kq + 4 * h;
      int o0 = (c0 ^ sw) * 16, o1 = ((c0 + 1) ^ sw) * 16;
      i32x8 af[2], bf[2];
      #pragma unroll
      for (int mi = 0; mi < 2; ++mi) af[mi] = ldfrag(Arow + mi * 32 * 128, o0, o1);
      #pragma unroll
      for (int ni = 0; ni < 2; ++ni) bf[ni] = ldfrag(Brow + ni * 32 * 128, o0, o1);
      #pragma unroll
      for (int mi = 0; mi < 2; ++mi)
        #pragma unroll
        for (int ni = 0; ni < 2; ++ni)
          acc[mi][ni] = __builtin_amdgcn_mfma_scale_f32_32x32x64_f8f6f4(
              af[mi], bf[ni], acc[mi][ni],
              0, 0, 0, 0x7F7F7F7F, 0, 0x7F7F7F7F);
    }
  }

  // Epilogue: C/D (32x32): col = lane&31, row = (reg&3)+8*(reg>>2)+4*(lane>>5).
  int col = lane & 31, half = lane >> 5;
  #pragma unroll
  for (int mi = 0; mi < 2; ++mi) {
    #pragma unroll
    for (int ni = 0; ni < 2; ++ni) {
      size_t ybase = (size_t)(y0 + wm * 64 + mi * 32 + 4 * half);
      size_t xg    = (size_t)(x0 + wn * 64 + ni * 32 + col);
      unsigned short* p = GT + ybase * GTS + xg;
      #pragma unroll
      for (int g = 0; g < 4; ++g)
        #pragma unroll
        for (int j = 0; j < 4; ++j) {
          unsigned int u = __float_as_uint(acc[mi][ni][4 * g + j]);
          unsigned short b = (unsigned short)((u + 0x7FFFu + ((u >> 16) & 1u)) >> 16);
          p[(size_t)(j + 8 * g) * GTS] = b;
        }
    }
  }
}

// ---------------------------------------------------------------------------
// 3b) G-path kernel 2: tap-sum + argmax, v5 (LDS-staged, FULL sj coverage).
//     resp[(qi,qj),(si,sj)] = sum_{dh,dw} GT[(si+dh)*96+sj+dw][(qi+dh)*96+qj+dw]
//     *** R9's v4 had a coverage BUG: sj groups of 12 covered only sj 0..46
//     (half the style range); it passed on threshold luck (absmax 0.0078 ==
//     the predicted loss shift from halving the argmax candidate set). ***
//     v5: full coverage (4 waves x sj-groups 24/24/24/22) and the block's
//     entire tap working set staged into LDS once:
//       3 bands x 96 rows x 192 B = 54 KiB  (band b = G rows (si+b)*96+r,
//       cols (qi+b)*96..+95), loaded with 3456 coalesced global_load_lds.
//     Tap reads then hit LDS at compile-time offsets (ds_read2-friendly):
//     per dh one vaddr (va += 192/iter); dwords at +0, +192, +196, +388.
//     Per-output accumulation is BIT-IDENTICAL to R6 (same unpacks, same f32
//     add order) -> absmax returns to ~0.
// ---------------------------------------------------------------------------
__global__ __launch_bounds__(256) void tapsum_kernel(
    const unsigned short* __restrict__ GT, const float* __restrict__ rnormS,
    unsigned long long* __restrict__ best) {
  __shared__ unsigned char glds[55296];            // 3 x 96 x 192 B
  __shared__ unsigned long long sm[4][96];
  // XCD-chunked bijective swizzle (m204): nwg=8836, q=1104, r=4.
  int orig = blockIdx.x;
  int xcd = orig & 7, idx = orig >> 3;
  int pid = (xcd < 4 ? xcd * 1105 : 4 * 1105 + (xcd - 4) * 1104) + idx;
  // Diagonal-major: consecutive pid -> (qi+1, si+1): shares 2/3 G bands.
  int d = pid / 94, pos = pid - d * 94;
  int qi = pos;
  int si = pos + d; if (si >= 94) si -= 94;

  int t = threadIdx.x;

  // ---- Stage: 3456 16-B chunks; chunk c = band*1152 + row*12 + seg ----
  const unsigned char* GTb = (const unsigned char*)GT;
  for (int k = 0; k < 14; ++k) {
    int c = k * 256 + t;
    if (c < 3456) {
      int b = c / 1152, rem = c - b * 1152;
      int r = rem / 12, s = rem - r * 12;
      size_t gaddr = ((size_t)((si + b) * 96 + r) * GTS + (size_t)(qi + b) * 96) * 2
                     + (size_t)s * 16;
      gl16(GTb + gaddr, glds + c * 16);
    }
  }
  __syncthreads();

  int w = t >> 6, l = t & 63;              // wave = sj-group (uniform)
  int sj0 = w * 24;
  int niter = (w == 3) ? 22 : 24;          // sj 0..23,24..47,48..71,72..93

  unsigned long long cand0 = 0ull, cand1 = 0ull;
  if (l < 47) {                            // lane l -> qj pair (2l, 2l+1)
    const float* rnp = rnormS + si * 94 + sj0;
    float bv0 = -3.0e38f, bv1 = -3.0e38f;
    int bs0 = sj0, bs1 = sj0;
    int va0 = sj0 * 192 + 4 * l;           // band 0 vaddr (bytes)
    int va1 = va0 + 18432;                 // band 1
    int va2 = va0 + 36864;                 // band 2
    for (int j = 0; j < niter; ++j) {
      // Per dh: d00 = (row sj, cols 2l..2l+1), d10 = (row sj+1, 2l..2l+1),
      //         d11 = (row sj+1, 2l+2..2l+3), d21 = (row sj+2, 2l+2..2l+3).
      unsigned int d00_0 = *(const unsigned int*)(glds + va0);
      unsigned int d10_0 = *(const unsigned int*)(glds + va0 + 192);
      unsigned int d11_0 = *(const unsigned int*)(glds + va0 + 196);
      unsigned int d21_0 = *(const unsigned int*)(glds + va0 + 388);
      unsigned int d00_1 = *(const unsigned int*)(glds + va1);
      unsigned int d10_1 = *(const unsigned int*)(glds + va1 + 192);
      unsigned int d11_1 = *(const unsigned int*)(glds + va1 + 196);
      unsigned int d21_1 = *(const unsigned int*)(glds + va1 + 388);
      unsigned int d00_2 = *(const unsigned int*)(glds + va2);
      unsigned int d10_2 = *(const unsigned int*)(glds + va2 + 192);
      unsigned int d11_2 = *(const unsigned int*)(glds + va2 + 196);
      unsigned int d21_2 = *(const unsigned int*)(glds + va2 + 388);
      float rn = rnp[j];

      // Output 0 (qj=2l): e=lo(d00), A=hi(d10), C=lo(d21).
      // R6 order: a0 = t00+t02+t11+t20+t22 ; a1 = t01+t10+t12+t21.
      float a0 = (((blo(d00_0) + blo(d21_0)) + bhi(d10_1)) + blo(d00_2)) + blo(d21_2);
      float a1 = ((bhi(d10_0) + blo(d00_1)) + blo(d21_1)) + bhi(d10_2);
      float v0 = (a0 + a1) * rn;
      // Output 1 (qj=2l+1): E=hi(d00), Bv=lo(d11), D=hi(d21).
      float a0b = (((bhi(d00_0) + bhi(d21_0)) + blo(d11_1)) + bhi(d00_2)) + bhi(d21_2);
      float a1b = ((blo(d11_0) + bhi(d00_1)) + bhi(d21_1)) + blo(d11_2);
      float v1 = (a0b + a1b) * rn;

      int sj = sj0 + j;
      if (v0 > bv0) { bv0 = v0; bs0 = sj; }
      if (v1 > bv1) { bv1 = v1; bs1 = sj; }
      va0 += 192; va1 += 192; va2 += 192;
    }
    {
      int s0i = si * 94 + bs0;
      cand0 = ((unsigned long long)ordf(bv0) << 32) |
              (unsigned long long)(0xFFFFFFFFu - (unsigned)s0i);
      int s1i = si * 94 + bs1;
      cand1 = ((unsigned long long)ordf(bv1) << 32) |
              (unsigned long long)(0xFFFFFFFFu - (unsigned)s1i);
    }
    sm[w][2 * l]     = cand0;
    sm[w][2 * l + 1] = cand1;
  }
  __syncthreads();
  if (t < 94) {
    unsigned long long c0 = sm[0][t], c1 = sm[1][t];
    unsigned long long c2 = sm[2][t], c3 = sm[3][t];
    unsigned long long ca = c0 > c1 ? c0 : c1;
    unsigned long long cb = c2 > c3 ? c2 : c3;
    unsigned long long c  = ca > cb ? ca : cb;   // ties -> smaller s (complement)
    atomicMax(best + (size_t)(qi * 94 + t) * 8, c);
  }
}

// ---------------------------------------------------------------------------
// 3c) Fallback: direct implicit-im2col GEMM+argmax (proven 265us path),
//     used when the workspace cannot hold GT.
// ---------------------------------------------------------------------------
__global__ __launch_bounds__(256, 2) void gemm_argmax_kernel(
    const unsigned char* __restrict__ TA, const unsigned char* __restrict__ TB,
    const float* __restrict__ rnormS, unsigned long long* __restrict__ best) {
  __shared__ unsigned char As[128 * 128];
  __shared__ unsigned char Bs[128 * 128];

  int orig = blockIdx.x;
  int xcd = orig & 7, idx = orig >> 3;
  int pid = (xcd < 4 ? xcd * 613 : 4 * 613 + (xcd - 4) * 612) + idx;

  int mt = pid % NTILE, nt = pid / NTILE;
  int q0 = mt * 128, s0 = nt * 128;
  int t = threadIdx.x, lane = t & 63, wave = t >> 6;
  int wm = wave >> 1, wn = wave & 1;

  int rr = t >> 3;
  int qc = (t & 7) ^ (rr & 7);
  const unsigned char* gA[4];
  const unsigned char* gB[4];
  #pragma unroll
  for (int i = 0; i < 4; ++i) {
    int qa = q0 + 32 * i + rr; if (qa > NP - 1) qa = NP - 1;
    int sa = s0 + 32 * i + rr; if (sa > NP - 1) sa = NP - 1;
    gA[i] = TA + (size_t)((qa / PW) * IW + (qa % PW)) * CH + qc * 16;
    gB[i] = TB + (size_t)((sa / PW) * IW + (sa % PW)) * CH + qc * 16;
  }
  unsigned char* lA = As + t * 16;
  unsigned char* lB = Bs + t * 16;

  f32x16 acc[2][2];
  #pragma unroll
  for (int mi = 0; mi < 2; ++mi)
    #pragma unroll
    for (int ni = 0; ni < 2; ++ni)
      #pragma unroll
      for (int j = 0; j < 16; ++j) acc[mi][ni][j] = 0.f;

  int kq = lane >> 5, sw = lane & 7;
  const unsigned char* Arow = As + (size_t)(wm * 64 + (lane & 31)) * 128;
  const unsigned char* Brow = Bs + (size_t)(wn * 64 + (lane & 31)) * 128;

  #pragma unroll 1
  for (int kt = 0; kt < KT2; ++kt) {
    int chunk = kt >> 1;
    int kh = chunk / 3, kw = chunk - kh * 3;
    int choff = (kh * IW + kw) * CH + (kt & 1) * 128;
    if (kt) __syncthreads();
    #pragma unroll
    for (int i = 0; i < 4; ++i) {
      gl16(gA[i] + choff, lA + i * 4096);
      gl16(gB[i] + choff, lB + i * 4096);
    }
    __syncthreads();
    #pragma unroll
    for (int h = 0; h < 2; ++h) {
      int c0 = 2 * kq + 4 * h;
      int o0 = (c0 ^ sw) * 16, o1 = ((c0 + 1) ^ sw) * 16;
      i32x8 af[2], bf[2];
      #pragma unroll
      for (int mi = 0; mi < 2; ++mi) af[mi] = ldfrag(Arow + mi * 32 * 128, o0, o1);
      #pragma unroll
      for (int ni = 0; ni < 2; ++ni) bf[ni] = ldfrag(Brow + ni * 32 * 128, o0, o1);
      #pragma unroll
      for (int mi = 0; mi < 2; ++mi)
        #pragma unroll
        for (int ni = 0; ni < 2; ++ni)
          acc[mi][ni] = __builtin_amdgcn_mfma_scale_f32_32x32x64_f8f6f4(
              af[mi], bf[ni], acc[mi][ni],
              0, 0, 0, 0x7F7F7F7F, 0, 0x7F7F7F7F);
    }
  }

  int col = lane & 31, half = lane >> 5;
  float rn[2]; int sc[2]; bool sv[2];
  #pragma unroll
  for (int ni = 0; ni < 2; ++ni) {
    int s = s0 + wn * 64 + ni * 32 + col;
    sc[ni] = s;
    sv[ni] = (s < NP);
    rn[ni] = sv[ni] ? rnormS[s] : 0.f;
  }
  #pragma unroll
  for (int mi = 0; mi < 2; ++mi) {
    #pragma unroll
    for (int reg = 0; reg < 16; ++reg) {
      unsigned long long p = 0ull;
      #pragma unroll
      for (int ni = 0; ni < 2; ++ni) {
        float v = acc[mi][ni][reg] * rn[ni];
        unsigned long long cand =
            ((unsigned long long)ordf(v) << 32) |
            (unsigned long long)(0xFFFFFFFFu - (unsigned)sc[ni]);
        cand = sv[ni] ? cand : 0ull;
        if (cand > p) p = cand;
      }
      #pragma unroll
      for (int sh = 16; sh >= 1; sh >>= 1) {
        unsigned long long o = __shfl_xor(p, sh, 64);
        if (o > p) p = o;
      }
      int q = q0 + wm * 64 + mi * 32 + (reg & 3) + 8 * (reg >> 2) + 4 * half;
      if (col == 0 && q < NP) atomicMax(best + (size_t)q * 8, p);
    }
  }
}

// ---------------------------------------------------------------------------
// 4) Final loss, parallel: 35 blocks, per-block partial sum, scaled atomicAdd.
//    (Single-block version was latency-serial: 8836 scattered 64B-stride
//    reads + gathers from one block.)
// ---------------------------------------------------------------------------
__global__ __launch_bounds__(256) void finalize_kernel(
    const unsigned long long* __restrict__ best,
    const float* __restrict__ normS,
    const float* __restrict__ normsqS,
    const float* __restrict__ synsq,
    float* __restrict__ out) {
  __shared__ float swv[4];
  int t = threadIdx.x;
  int q = blockIdx.x * 256 + t;
  float a = 0.f;
  if (q < NP) {
    unsigned long long p = best[(size_t)q * 8];
    unsigned int o   = (unsigned int)(p >> 32);
    unsigned int idx = 0xFFFFFFFFu - (unsigned int)(p & 0xFFFFFFFFull);
    unsigned int u   = (o & 0x80000000u) ? (o & 0x7FFFFFFFu) : ~o;
    float resp = __uint_as_float(u);
    float dot  = resp * normS[idx];
    a = (synsq[q] - 2.f * dot + normsqS[idx]) * (1.f / ((float)NP * 2304.f));
  }
  #pragma unroll
  for (int m = 32; m >= 1; m >>= 1) a += __shfl_xor(a, m, 64);
  if ((t & 63) == 0) swv[t >> 6] = a;
  __syncthreads();
  if (t == 0) atomicAdd(out, (swv[0] + swv[1]) + (swv[2] + swv[3]));
}

// ---------------------------------------------------------------------------
extern "C" void kernel_launch(void* const* d_in, const int* in_sizes, int n_in,
                              void* d_out, int out_size, void* d_ws, size_t ws_size,
                              hipStream_t stream) {
  const float* inA = (const float*)d_in[0];  // input  (synthesis)
  const float* inB = (const float*)d_in[1];  // target (style)
  float* out = (float*)d_out;

  char* ws = (char*)d_ws;
  unsigned char* TA = (unsigned char*)ws;                 // 2,359,296 B fp8
  unsigned char* TB = (unsigned char*)(ws + 2359296);     // 2,359,296 B fp8
  float* rnormS  = (float*)(ws + 4718592);
  float* normS   = (float*)(ws + 4718592 + 35344);
  float* normsqS = (float*)(ws + 4718592 + 70688);
  float* synsq   = (float*)(ws + 4718592 + 106032);
  unsigned long long* best = (unsigned long long*)(ws + 4718592 + 141376);
  // best padded: 64 B per q -> 565,504 B. GT (bf16 9216x9216) follows.
  const size_t GT_OFF = 4718592ull + 141376ull + 565504ull;   // 5,425,472
  unsigned short* GT = (unsigned short*)(ws + GT_OFF);
  const size_t NEED = GT_OFF + (size_t)NPIX * NPIX * 2;       // 175,294,784

  (void)hipMemsetAsync(best, 0, (size_t)NP * 64, stream);
  (void)hipMemsetAsync(out, 0, sizeof(float), stream);
  prep_kernel<<<dim3(1152), dim3(256), 0, stream>>>(inA, inB, (unsigned int*)TA, (unsigned int*)TB);
  norms_kernel<<<dim3((2 * NP + 3) / 4), dim3(256), 0, stream>>>(
      (const unsigned int*)TA, (const unsigned int*)TB, rnormS, normS, normsqS, synsq);
  if (ws_size >= NEED) {
    g_gemm_kernel<<<dim3(72 * 72), dim3(256), 0, stream>>>(TA, TB, GT);
    tapsum_kernel<<<dim3(NP), dim3(256), 0, stream>>>(GT, rnormS, best);
  } else {
    gemm_argmax_kernel<<<dim3(NWG), dim3(256), 0, stream>>>(TA, TB, rnormS, best);
  }
  finalize_kernel<<<dim3(35), dim3(256), 0, stream>>>(best, normS, normsqS, synsq, out);
}

// Round 11
// 216.470 us; speedup vs baseline: 1.0586x; 1.0586x over previous
//
#include <hip/hip_runtime.h>
#include <math.h>

// Problem constants
#define NP 8836          // number of patches per image (94*94)
#define PW 94            // patches per row
#define IW 96            // image width/height
#define CH 256           // channels
#define NTILE 70         // ceil(8836/128)  (fallback GEMM)
#define KT2 18           // fallback K tiles
#define NWG (NTILE * NTILE)
#define NPIX 9216        // 96*96 pixels
#define GTS 9216         // GT row stride in elements

typedef int   i32x4  __attribute__((ext_vector_type(4)));
typedef int   i32x8  __attribute__((ext_vector_type(8)));
typedef float f32x16 __attribute__((ext_vector_type(16)));

__device__ __forceinline__ unsigned int ordf(float f) {
  unsigned int u = __float_as_uint(f);
  return (u & 0x80000000u) ? ~u : (u | 0x80000000u);
}

__device__ __forceinline__ float blo(unsigned int x) {   // low bf16 -> f32 (exact)
  return __uint_as_float(x << 16);
}
__device__ __forceinline__ float bhi(unsigned int x) {   // high bf16 -> f32 (exact)
  return __uint_as_float(x & 0xFFFF0000u);
}

typedef const __attribute__((address_space(1))) void GvoidC;
typedef __attribute__((address_space(3))) void Lvoid;
__device__ __forceinline__ void gl16(const void* g, void* l) {
  __builtin_amdgcn_global_load_lds((GvoidC*)g, (Lvoid*)l, 16, 0, 0);
}

// ---------------------------------------------------------------------------
// 1) Convert+transpose [C, 9216] fp32 -> [9216, C] fp8 (HW v_cvt encoding).
// ---------------------------------------------------------------------------
__global__ __launch_bounds__(256) void prep_kernel(
    const float* __restrict__ inA, const float* __restrict__ inB,
    unsigned int* __restrict__ TA, unsigned int* __restrict__ TB) {
  __shared__ float tile[64][65];
  int bid = blockIdx.x;            // [0, 1152)
  const float* src; unsigned int* dst;
  if (bid < 576) { src = inA; dst = TA; }
  else           { src = inB; dst = TB; bid -= 576; }
  int cT  = bid & 3;        // c-tile   [0,4)  (64 channels)
  int xyT = bid >> 2;       // xy-tile  [0,144)
  int t = threadIdx.x;
  int l = t & 63, h = t >> 6;

  #pragma unroll
  for (int i = 0; i < 16; ++i) {
    int c = h * 16 + i;
    tile[c][l] = src[(size_t)(cT * 64 + c) * (IW * IW) + xyT * 64 + l];
  }
  __syncthreads();
  int cu = t & 15;          // u32 column within the 64-channel tile
  #pragma unroll
  for (int i = 0; i < 4; ++i) {
    int xy = (t >> 4) + i * 16;
    int c = cu * 4;
    unsigned int v = __builtin_amdgcn_cvt_pk_fp8_f32(tile[c][xy],     tile[c + 1][xy], 0, false);
    v              = __builtin_amdgcn_cvt_pk_fp8_f32(tile[c + 2][xy], tile[c + 3][xy], v, true);
    dst[(size_t)(xyT * 64 + xy) * 64 + cT * 16 + cu] = v;
  }
}

// ---------------------------------------------------------------------------
// 2) Per-patch squared norms from the fp8 images (consistent with GEMM dtype).
// ---------------------------------------------------------------------------
__global__ void norms_kernel(const unsigned int* __restrict__ TA, const unsigned int* __restrict__ TB,
                             float* __restrict__ rnormS, float* __restrict__ normS,
                             float* __restrict__ normsqS, float* __restrict__ synsq) {
  int wid  = blockIdx.x * 4 + (threadIdx.x >> 6);
  int lane = threadIdx.x & 63;
  bool isStyle = wid < NP;
  int p = isStyle ? wid : wid - NP;
  if (p >= NP) return;
  const unsigned int* T = isStyle ? TB : TA;
  int pi = p / PW, pj = p % PW;
  float s = 0.f;
  #pragma unroll
  for (int kh = 0; kh < 3; ++kh) {
    #pragma unroll
    for (int kw = 0; kw < 3; ++kw) {
      unsigned int v = T[(size_t)((pi + kh) * IW + (pj + kw)) * 64 + lane];
      float f0 = __builtin_amdgcn_cvt_f32_fp8(v, 0);
      float f1 = __builtin_amdgcn_cvt_f32_fp8(v, 1);
      float f2 = __builtin_amdgcn_cvt_f32_fp8(v, 2);
      float f3 = __builtin_amdgcn_cvt_f32_fp8(v, 3);
      s += f0 * f0 + f1 * f1 + f2 * f2 + f3 * f3;
    }
  }
  #pragma unroll
  for (int m = 32; m >= 1; m >>= 1) s += __shfl_xor(s, m, 64);
  if (lane == 0) {
    if (isStyle) {
      normsqS[p] = s;
      float n = sqrtf(s);
      normS[p]  = n;
      rnormS[p] = 1.f / n;
    } else {
      synsq[p] = s;
    }
  }
}

__device__ __forceinline__ i32x8 ldfrag(const unsigned char* rowp, int o0, int o1) {
  i32x4 lo = *(const i32x4*)(rowp + o0);
  i32x4 hi = *(const i32x4*)(rowp + o1);
  return __builtin_shufflevector(lo, hi, 0, 1, 2, 3, 4, 5, 6, 7);
}

// ---------------------------------------------------------------------------
// 3a) G-path kernel 1: pixel Gram GT[y][x] = sum_ch TB[y][ch]*TA[x][ch],
//     M=N=9216, K=256 (2 BK=128 steps), 128x128 tiles (72x72 grid), bf16 out.
//     bf16 storage + all-f32 tap summation is the R6-PROVEN numerics.
// ---------------------------------------------------------------------------
__global__ __launch_bounds__(256, 2) void g_gemm_kernel(
    const unsigned char* __restrict__ TA, const unsigned char* __restrict__ TB,
    unsigned short* __restrict__ GT) {
  __shared__ unsigned char As[128 * 128];
  __shared__ unsigned char Bs[128 * 128];

  // XCD-chunked bijective swizzle: 5184 = 8*648.
  int orig = blockIdx.x;
  int pid = (orig & 7) * 648 + (orig >> 3);
  int yt = pid % 72, xt = pid / 72;     // per-XCD chunk = 9 xt panels:
  int y0 = yt * 128, x0 = xt * 128;     // TB(2.4MB)+9 TA panels fit 4MB L2.
  int t = threadIdx.x, lane = t & 63, wave = t >> 6;
  int wm = wave >> 1, wn = wave & 1;

  int rr = t >> 3;
  int qc = (t & 7) ^ (rr & 7);
  const unsigned char* gA[4];
  const unsigned char* gB[4];
  #pragma unroll
  for (int i = 0; i < 4; ++i) {
    gA[i] = TB + (size_t)(y0 + 32 * i + rr) * CH + qc * 16;   // A-op = style y
    gB[i] = TA + (size_t)(x0 + 32 * i + rr) * CH + qc * 16;   // B-op = synth x
  }
  unsigned char* lA = As + t * 16;
  unsigned char* lB = Bs + t * 16;

  f32x16 acc[2][2];
  #pragma unroll
  for (int mi = 0; mi < 2; ++mi)
    #pragma unroll
    for (int ni = 0; ni < 2; ++ni)
      #pragma unroll
      for (int j = 0; j < 16; ++j) acc[mi][ni][j] = 0.f;

  int kq = lane >> 5, sw = lane & 7;
  const unsigned char* Arow = As + (size_t)(wm * 64 + (lane & 31)) * 128;
  const unsigned char* Brow = Bs + (size_t)(wn * 64 + (lane & 31)) * 128;

  #pragma unroll 1
  for (int kt = 0; kt < 2; ++kt) {
    int choff = kt * 128;
    if (kt) __syncthreads();
    #pragma unroll
    for (int i = 0; i < 4; ++i) {
      gl16(gA[i] + choff, lA + i * 4096);
      gl16(gB[i] + choff, lB + i * 4096);
    }
    __syncthreads();
    #pragma unroll
    for (int h = 0; h < 2; ++h) {
      int c0 = 2 * kq + 4 * h;
      int o0 = (c0 ^ sw) * 16, o1 = ((c0 + 1) ^ sw) * 16;
      i32x8 af[2], bf[2];
      #pragma unroll
      for (int mi = 0; mi < 2; ++mi) af[mi] = ldfrag(Arow + mi * 32 * 128, o0, o1);
      #pragma unroll
      for (int ni = 0; ni < 2; ++ni) bf[ni] = ldfrag(Brow + ni * 32 * 128, o0, o1);
      #pragma unroll
      for (int mi = 0; mi < 2; ++mi)
        #pragma unroll
        for (int ni = 0; ni < 2; ++ni)
          acc[mi][ni] = __builtin_amdgcn_mfma_scale_f32_32x32x64_f8f6f4(
              af[mi], bf[ni], acc[mi][ni],
              0, 0, 0, 0x7F7F7F7F, 0, 0x7F7F7F7F);
    }
  }

  // Epilogue: C/D (32x32): col = lane&31, row = (reg&3)+8*(reg>>2)+4*(lane>>5).
  int col = lane & 31, half = lane >> 5;
  #pragma unroll
  for (int mi = 0; mi < 2; ++mi) {
    #pragma unroll
    for (int ni = 0; ni < 2; ++ni) {
      size_t ybase = (size_t)(y0 + wm * 64 + mi * 32 + 4 * half);
      size_t xg    = (size_t)(x0 + wn * 64 + ni * 32 + col);
      unsigned short* p = GT + ybase * GTS + xg;
      #pragma unroll
      for (int g = 0; g < 4; ++g)
        #pragma unroll
        for (int j = 0; j < 4; ++j) {
          unsigned int u = __float_as_uint(acc[mi][ni][4 * g + j]);
          unsigned short b = (unsigned short)((u + 0x7FFFu + ((u >> 16) & 1u)) >> 16);
          p[(size_t)(j + 8 * g) * GTS] = b;
        }
    }
  }
}

// ---------------------------------------------------------------------------
// 3b) G-path kernel 2: tap-sum + argmax, v6 (v5 + 512-thread occupancy fix).
//     resp[(qi,qj),(si,sj)] = sum_{dh,dw} GT[(si+dh)*96+sj+dw][(qi+dh)*96+qj+dw]
//     R10 post-mortem: v5 (256 thr) ran at 20% occupancy (58 KiB LDS -> 2
//     blocks/CU -> only 2 waves/SIMD) and VALUBusy 67% — the VALU pipe idled
//     on LDS latency. v6 keeps the identical 54 KiB tile and BIT-IDENTICAL
//     per-output arithmetic (R6 f32 order — absmax 0.0 proven) but spreads
//     the work over 8 waves (sj-groups of 12; last group 10): same 2
//     blocks/CU but 16 waves/CU = 4 waves/SIMD.
// ---------------------------------------------------------------------------
__global__ __launch_bounds__(512) void tapsum_kernel(
    const unsigned short* __restrict__ GT, const float* __restrict__ rnormS,
    unsigned long long* __restrict__ best) {
  __shared__ unsigned char glds[55296];            // 3 x 96 x 192 B
  __shared__ unsigned long long sm[8][96];
  // XCD-chunked bijective swizzle (m204): nwg=8836, q=1104, r=4.
  int orig = blockIdx.x;
  int xcd = orig & 7, idx = orig >> 3;
  int pid = (xcd < 4 ? xcd * 1105 : 4 * 1105 + (xcd - 4) * 1104) + idx;
  // Diagonal-major: consecutive pid -> (qi+1, si+1): shares 2/3 G bands.
  int d = pid / 94, pos = pid - d * 94;
  int qi = pos;
  int si = pos + d; if (si >= 94) si -= 94;

  int t = threadIdx.x;

  // ---- Stage: 3456 16-B chunks; chunk c = band*1152 + row*12 + seg ----
  const unsigned char* GTb = (const unsigned char*)GT;
  for (int k = 0; k < 7; ++k) {
    int c = k * 512 + t;
    if (c < 3456) {
      int b = c / 1152, rem = c - b * 1152;
      int r = rem / 12, s = rem - r * 12;
      size_t gaddr = ((size_t)((si + b) * 96 + r) * GTS + (size_t)(qi + b) * 96) * 2
                     + (size_t)s * 16;
      gl16(GTb + gaddr, glds + c * 16);
    }
  }
  __syncthreads();

  int w = t >> 6, l = t & 63;              // wave = sj-group (uniform)
  int sj0 = w * 12;
  int niter = (w == 7) ? 10 : 12;          // sj 0..11, 12..23, ..., 84..93

  unsigned long long cand0 = 0ull, cand1 = 0ull;
  if (l < 47) {                            // lane l -> qj pair (2l, 2l+1)
    const float* rnp = rnormS + si * 94 + sj0;
    float bv0 = -3.0e38f, bv1 = -3.0e38f;
    int bs0 = sj0, bs1 = sj0;
    int va0 = sj0 * 192 + 4 * l;           // band 0 vaddr (bytes)
    int va1 = va0 + 18432;                 // band 1
    int va2 = va0 + 36864;                 // band 2
    for (int j = 0; j < niter; ++j) {
      // Per dh: d00 = (row sj, cols 2l..2l+1), d10 = (row sj+1, 2l..2l+1),
      //         d11 = (row sj+1, 2l+2..2l+3), d21 = (row sj+2, 2l+2..2l+3).
      unsigned int d00_0 = *(const unsigned int*)(glds + va0);
      unsigned int d10_0 = *(const unsigned int*)(glds + va0 + 192);
      unsigned int d11_0 = *(const unsigned int*)(glds + va0 + 196);
      unsigned int d21_0 = *(const unsigned int*)(glds + va0 + 388);
      unsigned int d00_1 = *(const unsigned int*)(glds + va1);
      unsigned int d10_1 = *(const unsigned int*)(glds + va1 + 192);
      unsigned int d11_1 = *(const unsigned int*)(glds + va1 + 196);
      unsigned int d21_1 = *(const unsigned int*)(glds + va1 + 388);
      unsigned int d00_2 = *(const unsigned int*)(glds + va2);
      unsigned int d10_2 = *(const unsigned int*)(glds + va2 + 192);
      unsigned int d11_2 = *(const unsigned int*)(glds + va2 + 196);
      unsigned int d21_2 = *(const unsigned int*)(glds + va2 + 388);
      float rn = rnp[j];

      // Output 0 (qj=2l): e=lo(d00), A=hi(d10), C=lo(d21).
      // R6 order: a0 = t00+t02+t11+t20+t22 ; a1 = t01+t10+t12+t21.
      float a0 = (((blo(d00_0) + blo(d21_0)) + bhi(d10_1)) + blo(d00_2)) + blo(d21_2);
      float a1 = ((bhi(d10_0) + blo(d00_1)) + blo(d21_1)) + bhi(d10_2);
      float v0 = (a0 + a1) * rn;
      // Output 1 (qj=2l+1): E=hi(d00), Bv=lo(d11), D=hi(d21).
      float a0b = (((bhi(d00_0) + bhi(d21_0)) + blo(d11_1)) + bhi(d00_2)) + bhi(d21_2);
      float a1b = ((blo(d11_0) + bhi(d00_1)) + bhi(d21_1)) + blo(d11_2);
      float v1 = (a0b + a1b) * rn;

      int sj = sj0 + j;
      if (v0 > bv0) { bv0 = v0; bs0 = sj; }
      if (v1 > bv1) { bv1 = v1; bs1 = sj; }
      va0 += 192; va1 += 192; va2 += 192;
    }
    {
      int s0i = si * 94 + bs0;
      cand0 = ((unsigned long long)ordf(bv0) << 32) |
              (unsigned long long)(0xFFFFFFFFu - (unsigned)s0i);
      int s1i = si * 94 + bs1;
      cand1 = ((unsigned long long)ordf(bv1) << 32) |
              (unsigned long long)(0xFFFFFFFFu - (unsigned)s1i);
    }
    sm[w][2 * l]     = cand0;
    sm[w][2 * l + 1] = cand1;
  }
  __syncthreads();
  if (t < 94) {
    unsigned long long c0 = sm[0][t], c1 = sm[1][t];
    unsigned long long c2 = sm[2][t], c3 = sm[3][t];
    unsigned long long c4 = sm[4][t], c5 = sm[5][t];
    unsigned long long c6 = sm[6][t], c7 = sm[7][t];
    unsigned long long ca = c0 > c1 ? c0 : c1;
    unsigned long long cb = c2 > c3 ? c2 : c3;
    unsigned long long cc = c4 > c5 ? c4 : c5;
    unsigned long long cd = c6 > c7 ? c6 : c7;
    ca = ca > cb ? ca : cb;
    cc = cc > cd ? cc : cd;
    unsigned long long c = ca > cc ? ca : cc;    // ties -> smaller s (complement)
    atomicMax(best + (size_t)(qi * 94 + t) * 8, c);
  }
}

// ---------------------------------------------------------------------------
// 3c) Fallback: direct implicit-im2col GEMM+argmax (proven 265us path),
//     used when the workspace cannot hold GT.
// ---------------------------------------------------------------------------
__global__ __launch_bounds__(256, 2) void gemm_argmax_kernel(
    const unsigned char* __restrict__ TA, const unsigned char* __restrict__ TB,
    const float* __restrict__ rnormS, unsigned long long* __restrict__ best) {
  __shared__ unsigned char As[128 * 128];
  __shared__ unsigned char Bs[128 * 128];

  int orig = blockIdx.x;
  int xcd = orig & 7, idx = orig >> 3;
  int pid = (xcd < 4 ? xcd * 613 : 4 * 613 + (xcd - 4) * 612) + idx;

  int mt = pid % NTILE, nt = pid / NTILE;
  int q0 = mt * 128, s0 = nt * 128;
  int t = threadIdx.x, lane = t & 63, wave = t >> 6;
  int wm = wave >> 1, wn = wave & 1;

  int rr = t >> 3;
  int qc = (t & 7) ^ (rr & 7);
  const unsigned char* gA[4];
  const unsigned char* gB[4];
  #pragma unroll
  for (int i = 0; i < 4; ++i) {
    int qa = q0 + 32 * i + rr; if (qa > NP - 1) qa = NP - 1;
    int sa = s0 + 32 * i + rr; if (sa > NP - 1) sa = NP - 1;
    gA[i] = TA + (size_t)((qa / PW) * IW + (qa % PW)) * CH + qc * 16;
    gB[i] = TB + (size_t)((sa / PW) * IW + (sa % PW)) * CH + qc * 16;
  }
  unsigned char* lA = As + t * 16;
  unsigned char* lB = Bs + t * 16;

  f32x16 acc[2][2];
  #pragma unroll
  for (int mi = 0; mi < 2; ++mi)
    #pragma unroll
    for (int ni = 0; ni < 2; ++ni)
      #pragma unroll
      for (int j = 0; j < 16; ++j) acc[mi][ni][j] = 0.f;

  int kq = lane >> 5, sw = lane & 7;
  const unsigned char* Arow = As + (size_t)(wm * 64 + (lane & 31)) * 128;
  const unsigned char* Brow = Bs + (size_t)(wn * 64 + (lane & 31)) * 128;

  #pragma unroll 1
  for (int kt = 0; kt < KT2; ++kt) {
    int chunk = kt >> 1;
    int kh = chunk / 3, kw = chunk - kh * 3;
    int choff = (kh * IW + kw) * CH + (kt & 1) * 128;
    if (kt) __syncthreads();
    #pragma unroll
    for (int i = 0; i < 4; ++i) {
      gl16(gA[i] + choff, lA + i * 4096);
      gl16(gB[i] + choff, lB + i * 4096);
    }
    __syncthreads();
    #pragma unroll
    for (int h = 0; h < 2; ++h) {
      int c0 = 2 * kq + 4 * h;
      int o0 = (c0 ^ sw) * 16, o1 = ((c0 + 1) ^ sw) * 16;
      i32x8 af[2], bf[2];
      #pragma unroll
      for (int mi = 0; mi < 2; ++mi) af[mi] = ldfrag(Arow + mi * 32 * 128, o0, o1);
      #pragma unroll
      for (int ni = 0; ni < 2; ++ni) bf[ni] = ldfrag(Brow + ni * 32 * 128, o0, o1);
      #pragma unroll
      for (int mi = 0; mi < 2; ++mi)
        #pragma unroll
        for (int ni = 0; ni < 2; ++ni)
          acc[mi][ni] = __builtin_amdgcn_mfma_scale_f32_32x32x64_f8f6f4(
              af[mi], bf[ni], acc[mi][ni],
              0, 0, 0, 0x7F7F7F7F, 0, 0x7F7F7F7F);
    }
  }

  int col = lane & 31, half = lane >> 5;
  float rn[2]; int sc[2]; bool sv[2];
  #pragma unroll
  for (int ni = 0; ni < 2; ++ni) {
    int s = s0 + wn * 64 + ni * 32 + col;
    sc[ni] = s;
    sv[ni] = (s < NP);
    rn[ni] = sv[ni] ? rnormS[s] : 0.f;
  }
  #pragma unroll
  for (int mi = 0; mi < 2; ++mi) {
    #pragma unroll
    for (int reg = 0; reg < 16; ++reg) {
      unsigned long long p = 0ull;
      #pragma unroll
      for (int ni = 0; ni < 2; ++ni) {
        float v = acc[mi][ni][reg] * rn[ni];
        unsigned long long cand =
            ((unsigned long long)ordf(v) << 32) |
            (unsigned long long)(0xFFFFFFFFu - (unsigned)sc[ni]);
        cand = sv[ni] ? cand : 0ull;
        if (cand > p) p = cand;
      }
      #pragma unroll
      for (int sh = 16; sh >= 1; sh >>= 1) {
        unsigned long long o = __shfl_xor(p, sh, 64);
        if (o > p) p = o;
      }
      int q = q0 + wm * 64 + mi * 32 + (reg & 3) + 8 * (reg >> 2) + 4 * half;
      if (col == 0 && q < NP) atomicMax(best + (size_t)q * 8, p);
    }
  }
}

// ---------------------------------------------------------------------------
// 4) Final loss, parallel: 35 blocks, per-block partial sum, scaled atomicAdd.
// ---------------------------------------------------------------------------
__global__ __launch_bounds__(256) void finalize_kernel(
    const unsigned long long* __restrict__ best,
    const float* __restrict__ normS,
    const float* __restrict__ normsqS,
    const float* __restrict__ synsq,
    float* __restrict__ out) {
  __shared__ float swv[4];
  int t = threadIdx.x;
  int q = blockIdx.x * 256 + t;
  float a = 0.f;
  if (q < NP) {
    unsigned long long p = best[(size_t)q * 8];
    unsigned int o   = (unsigned int)(p >> 32);
    unsigned int idx = 0xFFFFFFFFu - (unsigned int)(p & 0xFFFFFFFFull);
    unsigned int u   = (o & 0x80000000u) ? (o & 0x7FFFFFFFu) : ~o;
    float resp = __uint_as_float(u);
    float dot  = resp * normS[idx];
    a = (synsq[q] - 2.f * dot + normsqS[idx]) * (1.f / ((float)NP * 2304.f));
  }
  #pragma unroll
  for (int m = 32; m >= 1; m >>= 1) a += __shfl_xor(a, m, 64);
  if ((t & 63) == 0) swv[t >> 6] = a;
  __syncthreads();
  if (t == 0) atomicAdd(out, (swv[0] + swv[1]) + (swv[2] + swv[3]));
}

// ---------------------------------------------------------------------------
extern "C" void kernel_launch(void* const* d_in, const int* in_sizes, int n_in,
                              void* d_out, int out_size, void* d_ws, size_t ws_size,
                              hipStream_t stream) {
  const float* inA = (const float*)d_in[0];  // input  (synthesis)
  const float* inB = (const float*)d_in[1];  // target (style)
  float* out = (float*)d_out;

  char* ws = (char*)d_ws;
  unsigned char* TA = (unsigned char*)ws;                 // 2,359,296 B fp8
  unsigned char* TB = (unsigned char*)(ws + 2359296);     // 2,359,296 B fp8
  float* rnormS  = (float*)(ws + 4718592);
  float* normS   = (float*)(ws + 4718592 + 35344);
  float* normsqS = (float*)(ws + 4718592 + 70688);
  float* synsq   = (float*)(ws + 4718592 + 106032);
  unsigned long long* best = (unsigned long long*)(ws + 4718592 + 141376);
  // best padded: 64 B per q -> 565,504 B. GT (bf16 9216x9216) follows.
  const size_t GT_OFF = 4718592ull + 141376ull + 565504ull;   // 5,425,472
  unsigned short* GT = (unsigned short*)(ws + GT_OFF);
  const size_t NEED = GT_OFF + (size_t)NPIX * NPIX * 2;       // 175,294,784

  (void)hipMemsetAsync(best, 0, (size_t)NP * 64, stream);
  (void)hipMemsetAsync(out, 0, sizeof(float), stream);
  prep_kernel<<<dim3(1152), dim3(256), 0, stream>>>(inA, inB, (unsigned int*)TA, (unsigned int*)TB);
  norms_kernel<<<dim3((2 * NP + 3) / 4), dim3(256), 0, stream>>>(
      (const unsigned int*)TA, (const unsigned int*)TB, rnormS, normS, normsqS, synsq);
  if (ws_size >= NEED) {
    g_gemm_kernel<<<dim3(72 * 72), dim3(256), 0, stream>>>(TA, TB, GT);
    tapsum_kernel<<<dim3(NP), dim3(512), 0, stream>>>(GT, rnormS, best);
  } else {
    gemm_argmax_kernel<<<dim3(NWG), dim3(256), 0, stream>>>(TA, TB, rnormS, best);
  }
  finalize_kernel<<<dim3(35), dim3(256), 0, stream>>>(best, normS, normsqS, synsq, out);
}

// Round 13
// 211.566 us; speedup vs baseline: 1.0832x; 1.0232x over previous
//
#include <hip/hip_runtime.h>
#include <math.h>

// Problem constants
#define NP 8836          // number of patches per image (94*94)
#define PW 94            // patches per row
#define IW 96            // image width/height
#define CH 256           // channels
#define NTILE 70         // ceil(8836/128)  (fallback GEMM)
#define KT2 18           // fallback K tiles
#define NWG (NTILE * NTILE)
#define NPIX 9216        // 96*96 pixels
#define GTS 9216         // GT row stride in elements

typedef int   i32x4  __attribute__((ext_vector_type(4)));
typedef int   i32x8  __attribute__((ext_vector_type(8)));
typedef float f32x16 __attribute__((ext_vector_type(16)));

__device__ __forceinline__ unsigned int ordf(float f) {
  unsigned int u = __float_as_uint(f);
  return (u & 0x80000000u) ? ~u : (u | 0x80000000u);
}

__device__ __forceinline__ float blo(unsigned int x) {   // low bf16 -> f32 (exact)
  return __uint_as_float(x << 16);
}
__device__ __forceinline__ float bhi(unsigned int x) {   // high bf16 -> f32 (exact)
  return __uint_as_float(x & 0xFFFF0000u);
}

typedef const __attribute__((address_space(1))) void GvoidC;
typedef __attribute__((address_space(3))) void Lvoid;
__device__ __forceinline__ void gl16(const void* g, void* l) {
  __builtin_amdgcn_global_load_lds((GvoidC*)g, (Lvoid*)l, 16, 0, 0);
}

// ---------------------------------------------------------------------------
// 1) Convert+transpose [C, 9216] fp32 -> [9216, C] fp8 (HW v_cvt encoding).
// ---------------------------------------------------------------------------
__global__ __launch_bounds__(256) void prep_kernel(
    const float* __restrict__ inA, const float* __restrict__ inB,
    unsigned int* __restrict__ TA, unsigned int* __restrict__ TB) {
  __shared__ float tile[64][65];
  int bid = blockIdx.x;            // [0, 1152)
  const float* src; unsigned int* dst;
  if (bid < 576) { src = inA; dst = TA; }
  else           { src = inB; dst = TB; bid -= 576; }
  int cT  = bid & 3;        // c-tile   [0,4)  (64 channels)
  int xyT = bid >> 2;       // xy-tile  [0,144)
  int t = threadIdx.x;
  int l = t & 63, h = t >> 6;

  #pragma unroll
  for (int i = 0; i < 16; ++i) {
    int c = h * 16 + i;
    tile[c][l] = src[(size_t)(cT * 64 + c) * (IW * IW) + xyT * 64 + l];
  }
  __syncthreads();
  int cu = t & 15;          // u32 column within the 64-channel tile
  #pragma unroll
  for (int i = 0; i < 4; ++i) {
    int xy = (t >> 4) + i * 16;
    int c = cu * 4;
    unsigned int v = __builtin_amdgcn_cvt_pk_fp8_f32(tile[c][xy],     tile[c + 1][xy], 0, false);
    v              = __builtin_amdgcn_cvt_pk_fp8_f32(tile[c + 2][xy], tile[c + 3][xy], v, true);
    dst[(size_t)(xyT * 64 + xy) * 64 + cT * 16 + cu] = v;
  }
}

// ---------------------------------------------------------------------------
// 2) Per-patch squared norms from the fp8 images (consistent with GEMM dtype).
// ---------------------------------------------------------------------------
__global__ void norms_kernel(const unsigned int* __restrict__ TA, const unsigned int* __restrict__ TB,
                             float* __restrict__ rnormS, float* __restrict__ normS,
                             float* __restrict__ normsqS, float* __restrict__ synsq) {
  int wid  = blockIdx.x * 4 + (threadIdx.x >> 6);
  int lane = threadIdx.x & 63;
  bool isStyle = wid < NP;
  int p = isStyle ? wid : wid - NP;
  if (p >= NP) return;
  const unsigned int* T = isStyle ? TB : TA;
  int pi = p / PW, pj = p % PW;
  float s = 0.f;
  #pragma unroll
  for (int kh = 0; kh < 3; ++kh) {
    #pragma unroll
    for (int kw = 0; kw < 3; ++kw) {
      unsigned int v = T[(size_t)((pi + kh) * IW + (pj + kw)) * 64 + lane];
      float f0 = __builtin_amdgcn_cvt_f32_fp8(v, 0);
      float f1 = __builtin_amdgcn_cvt_f32_fp8(v, 1);
      float f2 = __builtin_amdgcn_cvt_f32_fp8(v, 2);
      float f3 = __builtin_amdgcn_cvt_f32_fp8(v, 3);
      s += f0 * f0 + f1 * f1 + f2 * f2 + f3 * f3;
    }
  }
  #pragma unroll
  for (int m = 32; m >= 1; m >>= 1) s += __shfl_xor(s, m, 64);
  if (lane == 0) {
    if (isStyle) {
      normsqS[p] = s;
      float n = sqrtf(s);
      normS[p]  = n;
      rnormS[p] = 1.f / n;
    } else {
      synsq[p] = s;
    }
  }
}

__device__ __forceinline__ i32x8 ldfrag(const unsigned char* rowp, int o0, int o1) {
  i32x4 lo = *(const i32x4*)(rowp + o0);
  i32x4 hi = *(const i32x4*)(rowp + o1);
  return __builtin_shufflevector(lo, hi, 0, 1, 2, 3, 4, 5, 6, 7);
}

// ---------------------------------------------------------------------------
// 3a) G-path kernel 1: pixel Gram GT[y][x] = sum_ch TB[y][ch]*TA[x][ch],
//     M=N=9216, K=256 (2 BK=128 steps), 128x128 tiles (72x72 grid), bf16 out.
//     bf16 storage + all-f32 tap summation is the R6-PROVEN numerics.
// ---------------------------------------------------------------------------
__global__ __launch_bounds__(256, 2) void g_gemm_kernel(
    const unsigned char* __restrict__ TA, const unsigned char* __restrict__ TB,
    unsigned short* __restrict__ GT) {
  __shared__ unsigned char As[128 * 128];
  __shared__ unsigned char Bs[128 * 128];

  // XCD-chunked bijective swizzle: 5184 = 8*648.
  int orig = blockIdx.x;
  int pid = (orig & 7) * 648 + (orig >> 3);
  int yt = pid % 72, xt = pid / 72;     // per-XCD chunk = 9 xt panels:
  int y0 = yt * 128, x0 = xt * 128;     // TB(2.4MB)+9 TA panels fit 4MB L2.
  int t = threadIdx.x, lane = t & 63, wave = t >> 6;
  int wm = wave >> 1, wn = wave & 1;

  int rr = t >> 3;
  int qc = (t & 7) ^ (rr & 7);
  const unsigned char* gA[4];
  const unsigned char* gB[4];
  #pragma unroll
  for (int i = 0; i < 4; ++i) {
    gA[i] = TB + (size_t)(y0 + 32 * i + rr) * CH + qc * 16;   // A-op = style y
    gB[i] = TA + (size_t)(x0 + 32 * i + rr) * CH + qc * 16;   // B-op = synth x
  }
  unsigned char* lA = As + t * 16;
  unsigned char* lB = Bs + t * 16;

  f32x16 acc[2][2];
  #pragma unroll
  for (int mi = 0; mi < 2; ++mi)
    #pragma unroll
    for (int ni = 0; ni < 2; ++ni)
      #pragma unroll
      for (int j = 0; j < 16; ++j) acc[mi][ni][j] = 0.f;

  int kq = lane >> 5, sw = lane & 7;
  const unsigned char* Arow = As + (size_t)(wm * 64 + (lane & 31)) * 128;
  const unsigned char* Brow = Bs + (size_t)(wn * 64 + (lane & 31)) * 128;

  #pragma unroll 1
  for (int kt = 0; kt < 2; ++kt) {
    int choff = kt * 128;
    if (kt) __syncthreads();
    #pragma unroll
    for (int i = 0; i < 4; ++i) {
      gl16(gA[i] + choff, lA + i * 4096);
      gl16(gB[i] + choff, lB + i * 4096);
    }
    __syncthreads();
    #pragma unroll
    for (int h = 0; h < 2; ++h) {
      int c0 = 2 * kq + 4 * h;
      int o0 = (c0 ^ sw) * 16, o1 = ((c0 + 1) ^ sw) * 16;
      i32x8 af[2], bf[2];
      #pragma unroll
      for (int mi = 0; mi < 2; ++mi) af[mi] = ldfrag(Arow + mi * 32 * 128, o0, o1);
      #pragma unroll
      for (int ni = 0; ni < 2; ++ni) bf[ni] = ldfrag(Brow + ni * 32 * 128, o0, o1);
      #pragma unroll
      for (int mi = 0; mi < 2; ++mi)
        #pragma unroll
        for (int ni = 0; ni < 2; ++ni)
          acc[mi][ni] = __builtin_amdgcn_mfma_scale_f32_32x32x64_f8f6f4(
              af[mi], bf[ni], acc[mi][ni],
              0, 0, 0, 0x7F7F7F7F, 0, 0x7F7F7F7F);
    }
  }

  // Epilogue: C/D (32x32): col = lane&31, row = (reg&3)+8*(reg>>2)+4*(lane>>5).
  int col = lane & 31, half = lane >> 5;
  #pragma unroll
  for (int mi = 0; mi < 2; ++mi) {
    #pragma unroll
    for (int ni = 0; ni < 2; ++ni) {
      size_t ybase = (size_t)(y0 + wm * 64 + mi * 32 + 4 * half);
      size_t xg    = (size_t)(x0 + wn * 64 + ni * 32 + col);
      unsigned short* p = GT + ybase * GTS + xg;
      #pragma unroll
      for (int g = 0; g < 4; ++g)
        #pragma unroll
        for (int j = 0; j < 4; ++j) {
          unsigned int u = __float_as_uint(acc[mi][ni][4 * g + j]);
          unsigned short b = (unsigned short)((u + 0x7FFFu + ((u >> 16) & 1u)) >> 16);
          p[(size_t)(j + 8 * g) * GTS] = b;
        }
    }
  }
}

// ---------------------------------------------------------------------------
// 3b) G-path kernel 2: tap-sum + argmax, v7 (full-lane work decomposition).
//     resp[(qi,qj),(si,sj)] = sum_{dh,dw} GT[(si+dh)*96+sj+dw][(qi+dh)*96+qj+dw]
//     R11 post-mortem: v6 wasted 17/64 lanes per wave (47 qj-pairs on 64
//     lanes, 73% util) and sat at 4 waves/SIMD, VALUBusy 77%.
//     v7: flatten work into 376 units = 8 sj-groups x 47 pairs; TWO lanes
//     per unit (sj split 6/6; unit (7,sub1) runs 4) over 768 threads:
//       u = t>>1, sub = t&1, g = u/47, p = u%47, sj0 = g*12 + sub*6.
//     -> 98% lane util (25% fewer wave-issue slots) and 12 waves/block x 2
//     blocks/CU = 6 waves/SIMD (LDS 66.4 KB). Per-iter tap loads, unpacks,
//     and f32 add order are BIT-IDENTICAL to v5/v6 (R6 numerics, absmax 0.0);
//     argmax partition-combine via packed-u64 max is exact.
//     (R12 bench was an infra failure — "container failed twice", no logs;
//     kernel re-audited for bounds/LDS/threads and resubmitted unchanged.)
// ---------------------------------------------------------------------------
__global__ __launch_bounds__(768) void tapsum_kernel(
    const unsigned short* __restrict__ GT, const float* __restrict__ rnormS,
    unsigned long long* __restrict__ best) {
  __shared__ unsigned char glds[55296];            // 3 x 96 x 192 B
  __shared__ unsigned long long sm[16][96];        // [g*2+sub][qj]
  __shared__ float rnlds[96];
  // XCD-chunked bijective swizzle (m204): nwg=8836, q=1104, r=4.
  int orig = blockIdx.x;
  int xcd = orig & 7, idx = orig >> 3;
  int pid = (xcd < 4 ? xcd * 1105 : 4 * 1105 + (xcd - 4) * 1104) + idx;
  // Diagonal-major: consecutive pid -> (qi+1, si+1): shares 2/3 G bands.
  int d = pid / 94, pos = pid - d * 94;
  int qi = pos;
  int si = pos + d; if (si >= 94) si -= 94;

  int t = threadIdx.x;

  // ---- Stage: 3456 16-B chunks; chunk c = band*1152 + row*12 + seg ----
  const unsigned char* GTb = (const unsigned char*)GT;
  #pragma unroll
  for (int k = 0; k < 5; ++k) {
    int c = k * 768 + t;
    if (c < 3456) {
      int b = c / 1152, rem = c - b * 1152;
      int r = rem / 12, s = rem - r * 12;
      size_t gaddr = ((size_t)((si + b) * 96 + r) * GTS + (size_t)(qi + b) * 96) * 2
                     + (size_t)s * 16;
      gl16(GTb + gaddr, glds + c * 16);
    }
  }
  if (t < 94) rnlds[t] = rnormS[si * 94 + t];
  __syncthreads();

  int u = t >> 1, sub = t & 1;
  if (u < 376) {
    int g = u / 47, p = u - g * 47;      // pair p -> qj (2p, 2p+1)
    int sj0 = g * 12 + sub * 6;
    int niter = (g == 7 && sub == 1) ? 4 : 6;   // sj 90..93 for the tail
    float bv0 = -3.0e38f, bv1 = -3.0e38f;
    int bs0 = sj0, bs1 = sj0;
    int va0 = sj0 * 192 + 4 * p;         // band 0 vaddr (bytes)
    int va1 = va0 + 18432;               // band 1
    int va2 = va0 + 36864;               // band 2
    for (int j = 0; j < niter; ++j) {
      // Per dh: d00 = (row sj, cols 2p..2p+1), d10 = (row sj+1, 2p..2p+1),
      //         d11 = (row sj+1, 2p+2..2p+3), d21 = (row sj+2, 2p+2..2p+3).
      unsigned int d00_0 = *(const unsigned int*)(glds + va0);
      unsigned int d10_0 = *(const unsigned int*)(glds + va0 + 192);
      unsigned int d11_0 = *(const unsigned int*)(glds + va0 + 196);
      unsigned int d21_0 = *(const unsigned int*)(glds + va0 + 388);
      unsigned int d00_1 = *(const unsigned int*)(glds + va1);
      unsigned int d10_1 = *(const unsigned int*)(glds + va1 + 192);
      unsigned int d11_1 = *(const unsigned int*)(glds + va1 + 196);
      unsigned int d21_1 = *(const unsigned int*)(glds + va1 + 388);
      unsigned int d00_2 = *(const unsigned int*)(glds + va2);
      unsigned int d10_2 = *(const unsigned int*)(glds + va2 + 192);
      unsigned int d11_2 = *(const unsigned int*)(glds + va2 + 196);
      unsigned int d21_2 = *(const unsigned int*)(glds + va2 + 388);
      float rn = rnlds[sj0 + j];

      // Output 0 (qj=2p): e=lo(d00), A=hi(d10), C=lo(d21).
      // R6 order: a0 = t00+t02+t11+t20+t22 ; a1 = t01+t10+t12+t21.
      float a0 = (((blo(d00_0) + blo(d21_0)) + bhi(d10_1)) + blo(d00_2)) + blo(d21_2);
      float a1 = ((bhi(d10_0) + blo(d00_1)) + blo(d21_1)) + bhi(d10_2);
      float v0 = (a0 + a1) * rn;
      // Output 1 (qj=2p+1): E=hi(d00), Bv=lo(d11), D=hi(d21).
      float a0b = (((bhi(d00_0) + bhi(d21_0)) + blo(d11_1)) + bhi(d00_2)) + bhi(d21_2);
      float a1b = ((blo(d11_0) + bhi(d00_1)) + bhi(d21_1)) + blo(d11_2);
      float v1 = (a0b + a1b) * rn;

      int sj = sj0 + j;
      if (v0 > bv0) { bv0 = v0; bs0 = sj; }
      if (v1 > bv1) { bv1 = v1; bs1 = sj; }
      va0 += 192; va1 += 192; va2 += 192;
    }
    int s0i = si * 94 + bs0;
    unsigned long long cand0 = ((unsigned long long)ordf(bv0) << 32) |
                               (unsigned long long)(0xFFFFFFFFu - (unsigned)s0i);
    int s1i = si * 94 + bs1;
    unsigned long long cand1 = ((unsigned long long)ordf(bv1) << 32) |
                               (unsigned long long)(0xFFFFFFFFu - (unsigned)s1i);
    sm[g * 2 + sub][2 * p]     = cand0;
    sm[g * 2 + sub][2 * p + 1] = cand1;
  }
  __syncthreads();
  if (t < 94) {
    unsigned long long c = sm[0][t];
    #pragma unroll
    for (int r = 1; r < 16; ++r) {
      unsigned long long o = sm[r][t];
      if (o > c) c = o;                  // ties -> smaller s (complement)
    }
    atomicMax(best + (size_t)(qi * 94 + t) * 8, c);
  }
}

// ---------------------------------------------------------------------------
// 3c) Fallback: direct implicit-im2col GEMM+argmax (proven 265us path),
//     used when the workspace cannot hold GT.
// ---------------------------------------------------------------------------
__global__ __launch_bounds__(256, 2) void gemm_argmax_kernel(
    const unsigned char* __restrict__ TA, const unsigned char* __restrict__ TB,
    const float* __restrict__ rnormS, unsigned long long* __restrict__ best) {
  __shared__ unsigned char As[128 * 128];
  __shared__ unsigned char Bs[128 * 128];

  int orig = blockIdx.x;
  int xcd = orig & 7, idx = orig >> 3;
  int pid = (xcd < 4 ? xcd * 613 : 4 * 613 + (xcd - 4) * 612) + idx;

  int mt = pid % NTILE, nt = pid / NTILE;
  int q0 = mt * 128, s0 = nt * 128;
  int t = threadIdx.x, lane = t & 63, wave = t >> 6;
  int wm = wave >> 1, wn = wave & 1;

  int rr = t >> 3;
  int qc = (t & 7) ^ (rr & 7);
  const unsigned char* gA[4];
  const unsigned char* gB[4];
  #pragma unroll
  for (int i = 0; i < 4; ++i) {
    int qa = q0 + 32 * i + rr; if (qa > NP - 1) qa = NP - 1;
    int sa = s0 + 32 * i + rr; if (sa > NP - 1) sa = NP - 1;
    gA[i] = TA + (size_t)((qa / PW) * IW + (qa % PW)) * CH + qc * 16;
    gB[i] = TB + (size_t)((sa / PW) * IW + (sa % PW)) * CH + qc * 16;
  }
  unsigned char* lA = As + t * 16;
  unsigned char* lB = Bs + t * 16;

  f32x16 acc[2][2];
  #pragma unroll
  for (int mi = 0; mi < 2; ++mi)
    #pragma unroll
    for (int ni = 0; ni < 2; ++ni)
      #pragma unroll
      for (int j = 0; j < 16; ++j) acc[mi][ni][j] = 0.f;

  int kq = lane >> 5, sw = lane & 7;
  const unsigned char* Arow = As + (size_t)(wm * 64 + (lane & 31)) * 128;
  const unsigned char* Brow = Bs + (size_t)(wn * 64 + (lane & 31)) * 128;

  #pragma unroll 1
  for (int kt = 0; kt < KT2; ++kt) {
    int chunk = kt >> 1;
    int kh = chunk / 3, kw = chunk - kh * 3;
    int choff = (kh * IW + kw) * CH + (kt & 1) * 128;
    if (kt) __syncthreads();
    #pragma unroll
    for (int i = 0; i < 4; ++i) {
      gl16(gA[i] + choff, lA + i * 4096);
      gl16(gB[i] + choff, lB + i * 4096);
    }
    __syncthreads();
    #pragma unroll
    for (int h = 0; h < 2; ++h) {
      int c0 = 2 * kq + 4 * h;
      int o0 = (c0 ^ sw) * 16, o1 = ((c0 + 1) ^ sw) * 16;
      i32x8 af[2], bf[2];
      #pragma unroll
      for (int mi = 0; mi < 2; ++mi) af[mi] = ldfrag(Arow + mi * 32 * 128, o0, o1);
      #pragma unroll
      for (int ni = 0; ni < 2; ++ni) bf[ni] = ldfrag(Brow + ni * 32 * 128, o0, o1);
      #pragma unroll
      for (int mi = 0; mi < 2; ++mi)
        #pragma unroll
        for (int ni = 0; ni < 2; ++ni)
          acc[mi][ni] = __builtin_amdgcn_mfma_scale_f32_32x32x64_f8f6f4(
              af[mi], bf[ni], acc[mi][ni],
              0, 0, 0, 0x7F7F7F7F, 0, 0x7F7F7F7F);
    }
  }

  int col = lane & 31, half = lane >> 5;
  float rn[2]; int sc[2]; bool sv[2];
  #pragma unroll
  for (int ni = 0; ni < 2; ++ni) {
    int s = s0 + wn * 64 + ni * 32 + col;
    sc[ni] = s;
    sv[ni] = (s < NP);
    rn[ni] = sv[ni] ? rnormS[s] : 0.f;
  }
  #pragma unroll
  for (int mi = 0; mi < 2; ++mi) {
    #pragma unroll
    for (int reg = 0; reg < 16; ++reg) {
      unsigned long long p = 0ull;
      #pragma unroll
      for (int ni = 0; ni < 2; ++ni) {
        float v = acc[mi][ni][reg] * rn[ni];
        unsigned long long cand =
            ((unsigned long long)ordf(v) << 32) |
            (unsigned long long)(0xFFFFFFFFu - (unsigned)sc[ni]);
        cand = sv[ni] ? cand : 0ull;
        if (cand > p) p = cand;
      }
      #pragma unroll
      for (int sh = 16; sh >= 1; sh >>= 1) {
        unsigned long long o = __shfl_xor(p, sh, 64);
        if (o > p) p = o;
      }
      int q = q0 + wm * 64 + mi * 32 + (reg & 3) + 8 * (reg >> 2) + 4 * half;
      if (col == 0 && q < NP) atomicMax(best + (size_t)q * 8, p);
    }
  }
}

// ---------------------------------------------------------------------------
// 4) Final loss, parallel: 35 blocks, per-block partial sum, scaled atomicAdd.
// ---------------------------------------------------------------------------
__global__ __launch_bounds__(256) void finalize_kernel(
    const unsigned long long* __restrict__ best,
    const float* __restrict__ normS,
    const float* __restrict__ normsqS,
    const float* __restrict__ synsq,
    float* __restrict__ out) {
  __shared__ float swv[4];
  int t = threadIdx.x;
  int q = blockIdx.x * 256 + t;
  float a = 0.f;
  if (q < NP) {
    unsigned long long p = best[(size_t)q * 8];
    unsigned int o   = (unsigned int)(p >> 32);
    unsigned int idx = 0xFFFFFFFFu - (unsigned int)(p & 0xFFFFFFFFull);
    unsigned int u   = (o & 0x80000000u) ? (o & 0x7FFFFFFFu) : ~o;
    float resp = __uint_as_float(u);
    float dot  = resp * normS[idx];
    a = (synsq[q] - 2.f * dot + normsqS[idx]) * (1.f / ((float)NP * 2304.f));
  }
  #pragma unroll
  for (int m = 32; m >= 1; m >>= 1) a += __shfl_xor(a, m, 64);
  if ((t & 63) == 0) swv[t >> 6] = a;
  __syncthreads();
  if (t == 0) atomicAdd(out, (swv[0] + swv[1]) + (swv[2] + swv[3]));
}

// ---------------------------------------------------------------------------
extern "C" void kernel_launch(void* const* d_in, const int* in_sizes, int n_in,
                              void* d_out, int out_size, void* d_ws, size_t ws_size,
                              hipStream_t stream) {
  const float* inA = (const float*)d_in[0];  // input  (synthesis)
  const float* inB = (const float*)d_in[1];  // target (style)
  float* out = (float*)d_out;

  char* ws = (char*)d_ws;
  unsigned char* TA = (unsigned char*)ws;                 // 2,359,296 B fp8
  unsigned char* TB = (unsigned char*)(ws + 2359296);     // 2,359,296 B fp8
  float* rnormS  = (float*)(ws + 4718592);
  float* normS   = (float*)(ws + 4718592 + 35344);
  float* normsqS = (float*)(ws + 4718592 + 70688);
  float* synsq   = (float*)(ws + 4718592 + 106032);
  unsigned long long* best = (unsigned long long*)(ws + 4718592 + 141376);
  // best padded: 64 B per q -> 565,504 B. GT (bf16 9216x9216) follows.
  const size_t GT_OFF = 4718592ull + 141376ull + 565504ull;   // 5,425,472
  unsigned short* GT = (unsigned short*)(ws + GT_OFF);
  const size_t NEED = GT_OFF + (size_t)NPIX * NPIX * 2;       // 175,294,784

  (void)hipMemsetAsync(best, 0, (size_t)NP * 64, stream);
  (void)hipMemsetAsync(out, 0, sizeof(float), stream);
  prep_kernel<<<dim3(1152), dim3(256), 0, stream>>>(inA, inB, (unsigned int*)TA, (unsigned int*)TB);
  norms_kernel<<<dim3((2 * NP + 3) / 4), dim3(256), 0, stream>>>(
      (const unsigned int*)TA, (const unsigned int*)TB, rnormS, normS, normsqS, synsq);
  if (ws_size >= NEED) {
    g_gemm_kernel<<<dim3(72 * 72), dim3(256), 0, stream>>>(TA, TB, GT);
    tapsum_kernel<<<dim3(NP), dim3(768), 0, stream>>>(GT, rnormS, best);
  } else {
    gemm_argmax_kernel<<<dim3(NWG), dim3(256), 0, stream>>>(TA, TB, rnormS, best);
  }
  finalize_kernel<<<dim3(35), dim3(256), 0, stream>>>(best, normS, normsqS, synsq, out);
}

// Round 15
// 192.660 us; speedup vs baseline: 1.1895x; 1.0981x over previous
//
#include <hip/hip_runtime.h>
#include <math.h>

// Problem constants
#define NP 8836          // number of patches per image (94*94)
#define PW 94            // patches per row
#define IW 96            // image width/height
#define CH 256           // channels
#define NTILE 70         // ceil(8836/128)  (fallback GEMM)
#define KT2 18           // fallback K tiles
#define NWG (NTILE * NTILE)
#define NPIX 9216        // 96*96 pixels
#define GTS 9216         // GT row stride in elements

typedef int   i32x4  __attribute__((ext_vector_type(4)));
typedef int   i32x8  __attribute__((ext_vector_type(8)));
typedef float f32x16 __attribute__((ext_vector_type(16)));

__device__ __forceinline__ unsigned int ordf(float f) {
  unsigned int u = __float_as_uint(f);
  return (u & 0x80000000u) ? ~u : (u | 0x80000000u);
}

__device__ __forceinline__ float blo(unsigned int x) {   // low bf16 -> f32 (exact)
  return __uint_as_float(x << 16);
}
__device__ __forceinline__ float bhi(unsigned int x) {   // high bf16 -> f32 (exact)
  return __uint_as_float(x & 0xFFFF0000u);
}

typedef const __attribute__((address_space(1))) void GvoidC;
typedef __attribute__((address_space(3))) void Lvoid;
__device__ __forceinline__ void gl16(const void* g, void* l) {
  __builtin_amdgcn_global_load_lds((GvoidC*)g, (Lvoid*)l, 16, 0, 0);
}

// ---------------------------------------------------------------------------
// 1) Convert+transpose [C, 9216] fp32 -> [9216, C] fp8 (HW v_cvt encoding).
// ---------------------------------------------------------------------------
__global__ __launch_bounds__(256) void prep_kernel(
    const float* __restrict__ inA, const float* __restrict__ inB,
    unsigned int* __restrict__ TA, unsigned int* __restrict__ TB) {
  __shared__ float tile[64][65];
  int bid = blockIdx.x;            // [0, 1152)
  const float* src; unsigned int* dst;
  if (bid < 576) { src = inA; dst = TA; }
  else           { src = inB; dst = TB; bid -= 576; }
  int cT  = bid & 3;        // c-tile   [0,4)  (64 channels)
  int xyT = bid >> 2;       // xy-tile  [0,144)
  int t = threadIdx.x;
  int l = t & 63, h = t >> 6;

  #pragma unroll
  for (int i = 0; i < 16; ++i) {
    int c = h * 16 + i;
    tile[c][l] = src[(size_t)(cT * 64 + c) * (IW * IW) + xyT * 64 + l];
  }
  __syncthreads();
  int cu = t & 15;          // u32 column within the 64-channel tile
  #pragma unroll
  for (int i = 0; i < 4; ++i) {
    int xy = (t >> 4) + i * 16;
    int c = cu * 4;
    unsigned int v = __builtin_amdgcn_cvt_pk_fp8_f32(tile[c][xy],     tile[c + 1][xy], 0, false);
    v              = __builtin_amdgcn_cvt_pk_fp8_f32(tile[c + 2][xy], tile[c + 3][xy], v, true);
    dst[(size_t)(xyT * 64 + xy) * 64 + cT * 16 + cu] = v;
  }
}

// ---------------------------------------------------------------------------
// 2) Per-patch squared norms from the fp8 images (consistent with GEMM dtype).
// ---------------------------------------------------------------------------
__global__ void norms_kernel(const unsigned int* __restrict__ TA, const unsigned int* __restrict__ TB,
                             float* __restrict__ rnormS, float* __restrict__ normS,
                             float* __restrict__ normsqS, float* __restrict__ synsq) {
  int wid  = blockIdx.x * 4 + (threadIdx.x >> 6);
  int lane = threadIdx.x & 63;
  bool isStyle = wid < NP;
  int p = isStyle ? wid : wid - NP;
  if (p >= NP) return;
  const unsigned int* T = isStyle ? TB : TA;
  int pi = p / PW, pj = p % PW;
  float s = 0.f;
  #pragma unroll
  for (int kh = 0; kh < 3; ++kh) {
    #pragma unroll
    for (int kw = 0; kw < 3; ++kw) {
      unsigned int v = T[(size_t)((pi + kh) * IW + (pj + kw)) * 64 + lane];
      float f0 = __builtin_amdgcn_cvt_f32_fp8(v, 0);
      float f1 = __builtin_amdgcn_cvt_f32_fp8(v, 1);
      float f2 = __builtin_amdgcn_cvt_f32_fp8(v, 2);
      float f3 = __builtin_amdgcn_cvt_f32_fp8(v, 3);
      s += f0 * f0 + f1 * f1 + f2 * f2 + f3 * f3;
    }
  }
  #pragma unroll
  for (int m = 32; m >= 1; m >>= 1) s += __shfl_xor(s, m, 64);
  if (lane == 0) {
    if (isStyle) {
      normsqS[p] = s;
      float n = sqrtf(s);
      normS[p]  = n;
      rnormS[p] = 1.f / n;
    } else {
      synsq[p] = s;
    }
  }
}

__device__ __forceinline__ i32x8 ldfrag(const unsigned char* rowp, int o0, int o1) {
  i32x4 lo = *(const i32x4*)(rowp + o0);
  i32x4 hi = *(const i32x4*)(rowp + o1);
  return __builtin_shufflevector(lo, hi, 0, 1, 2, 3, 4, 5, 6, 7);
}

// ---------------------------------------------------------------------------
// 3a) G-path kernel 1: pixel Gram GT[y][x] = sum_ch TB[y][ch]*TA[x][ch],
//     M=N=9216, K=256 (2 BK=128 steps), 128x128 tiles (72x72 grid), bf16 out.
// ---------------------------------------------------------------------------
__global__ __launch_bounds__(256, 2) void g_gemm_kernel(
    const unsigned char* __restrict__ TA, const unsigned char* __restrict__ TB,
    unsigned short* __restrict__ GT) {
  __shared__ unsigned char As[128 * 128];
  __shared__ unsigned char Bs[128 * 128];

  // XCD-chunked bijective swizzle: 5184 = 8*648.
  int orig = blockIdx.x;
  int pid = (orig & 7) * 648 + (orig >> 3);
  int yt = pid % 72, xt = pid / 72;     // per-XCD chunk = 9 xt panels:
  int y0 = yt * 128, x0 = xt * 128;     // TB(2.4MB)+9 TA panels fit 4MB L2.
  int t = threadIdx.x, lane = t & 63, wave = t >> 6;
  int wm = wave >> 1, wn = wave & 1;

  int rr = t >> 3;
  int qc = (t & 7) ^ (rr & 7);
  const unsigned char* gA[4];
  const unsigned char* gB[4];
  #pragma unroll
  for (int i = 0; i < 4; ++i) {
    gA[i] = TB + (size_t)(y0 + 32 * i + rr) * CH + qc * 16;   // A-op = style y
    gB[i] = TA + (size_t)(x0 + 32 * i + rr) * CH + qc * 16;   // B-op = synth x
  }
  unsigned char* lA = As + t * 16;
  unsigned char* lB = Bs + t * 16;

  f32x16 acc[2][2];
  #pragma unroll
  for (int mi = 0; mi < 2; ++mi)
    #pragma unroll
    for (int ni = 0; ni < 2; ++ni)
      #pragma unroll
      for (int j = 0; j < 16; ++j) acc[mi][ni][j] = 0.f;

  int kq = lane >> 5, sw = lane & 7;
  const unsigned char* Arow = As + (size_t)(wm * 64 + (lane & 31)) * 128;
  const unsigned char* Brow = Bs + (size_t)(wn * 64 + (lane & 31)) * 128;

  #pragma unroll 1
  for (int kt = 0; kt < 2; ++kt) {
    int choff = kt * 128;
    if (kt) __syncthreads();
    #pragma unroll
    for (int i = 0; i < 4; ++i) {
      gl16(gA[i] + choff, lA + i * 4096);
      gl16(gB[i] + choff, lB + i * 4096);
    }
    __syncthreads();
    #pragma unroll
    for (int h = 0; h < 2; ++h) {
      int c0 = 2 * kq + 4 * h;
      int o0 = (c0 ^ sw) * 16, o1 = ((c0 + 1) ^ sw) * 16;
      i32x8 af[2], bf[2];
      #pragma unroll
      for (int mi = 0; mi < 2; ++mi) af[mi] = ldfrag(Arow + mi * 32 * 128, o0, o1);
      #pragma unroll
      for (int ni = 0; ni < 2; ++ni) bf[ni] = ldfrag(Brow + ni * 32 * 128, o0, o1);
      #pragma unroll
      for (int mi = 0; mi < 2; ++mi)
        #pragma unroll
        for (int ni = 0; ni < 2; ++ni)
          acc[mi][ni] = __builtin_amdgcn_mfma_scale_f32_32x32x64_f8f6f4(
              af[mi], bf[ni], acc[mi][ni],
              0, 0, 0, 0x7F7F7F7F, 0, 0x7F7F7F7F);
    }
  }

  // Epilogue: C/D (32x32): col = lane&31, row = (reg&3)+8*(reg>>2)+4*(lane>>5).
  int col = lane & 31, half = lane >> 5;
  #pragma unroll
  for (int mi = 0; mi < 2; ++mi) {
    #pragma unroll
    for (int ni = 0; ni < 2; ++ni) {
      size_t ybase = (size_t)(y0 + wm * 64 + mi * 32 + 4 * half);
      size_t xg    = (size_t)(x0 + wn * 64 + ni * 32 + col);
      unsigned short* p = GT + ybase * GTS + xg;
      #pragma unroll
      for (int g = 0; g < 4; ++g)
        #pragma unroll
        for (int j = 0; j < 4; ++j) {
          unsigned int u = __float_as_uint(acc[mi][ni][4 * g + j]);
          unsigned short b = (unsigned short)((u + 0x7FFFu + ((u >> 16) & 1u)) >> 16);
          p[(size_t)(j + 8 * g) * GTS] = b;
        }
    }
  }
}

// ---------------------------------------------------------------------------
// 3b) G-path kernel 2: tap-sum + argmax, v8 (band-sum factorization).
//     resp[(qi,qj),(si,sj)] = sum_{dh,dw} GT[(si+dh)*96+sj+dw][(qi+dh)*96+qj+dw]
//     KEY: the dh-sum is (sj,qj)-INDEPENDENT. Precompute per block
//       S[r][c] = sum_{b=0..2} GT[(si+b)*96+r][(qi+b)*96+c]   (f32, LDS)
//     once (9216 entries, ~2 ops/output amortized); then each output is just
//       resp = (S[sj][qj] + S[sj+1][qj+1] + S[sj+2][qj+2]) * rn
//     — 3 taps instead of 9 (v7 burned ~45 VALU + 12 LDS per 2 outputs, and
//     its lane pairing aliased banks: 2.26e7 conflicts. v8: ~5 VALU + 3 LDS
//     per output; lanes map to consecutive qj -> 2-way bank access = free).
//     Numerics: summation ORDER differs from R6 but all adds are f32 on
//     exact bf16 promotions: error ~1e-5 in raw resp -> ~2e-7 normalized ->
//     argmax flips only at exact ties; loss shift << 1e-4 vs threshold 3.7e-2
//     (calibration: R9's half-coverage bug shifted only 7.8e-3).
//     Layout: 768 thr; lane t<752 owns (g=t/94, qj=t%94), walks 12 sj
//     (g=7: 10); sm[8][96] packed-u64 reduction (exact argmax combine).
//     (R14 bench was the session's second "container failed twice" infra
//     error — same message as R12, whose unchanged resubmission then passed.
//     Kernel re-audited (bounds/LDS/threads all legal) and resubmitted
//     unchanged. A third identical failure would implicate the kernel.)
// ---------------------------------------------------------------------------
__global__ __launch_bounds__(768) void tapsum_kernel(
    const unsigned short* __restrict__ GT, const float* __restrict__ rnormS,
    unsigned long long* __restrict__ best) {
  __shared__ float S[96 * 96];                     // 36,864 B
  __shared__ unsigned long long sm[8][96];         // 6,144 B
  __shared__ float rnlds[96];
  // XCD-chunked bijective swizzle (m204): nwg=8836, q=1104, r=4.
  int orig = blockIdx.x;
  int xcd = orig & 7, idx = orig >> 3;
  int pid = (xcd < 4 ? xcd * 1105 : 4 * 1105 + (xcd - 4) * 1104) + idx;
  // Diagonal-major: consecutive pid -> (qi+1, si+1): shares 2/3 G bands.
  int d = pid / 94, pos = pid - d * 94;
  int qi = pos;
  int si = pos + d; if (si >= 94) si -= 94;

  int t = threadIdx.x;

  // ---- Precompute S: 4608 dword-pairs, 6 per thread, coalesced rows ----
  const unsigned char* GTb = (const unsigned char*)GT;
  #pragma unroll
  for (int k = 0; k < 6; ++k) {
    int p2 = t + k * 768;                          // 0..4607
    int r = p2 / 48, cp = p2 - r * 48;             // c = 2*cp
    unsigned int d0 = *(const unsigned int*)(GTb +
        ((size_t)((si + 0) * 96 + r) * GTS + (size_t)(qi + 0) * 96 + 2 * cp) * 2);
    unsigned int d1 = *(const unsigned int*)(GTb +
        ((size_t)((si + 1) * 96 + r) * GTS + (size_t)(qi + 1) * 96 + 2 * cp) * 2);
    unsigned int d2 = *(const unsigned int*)(GTb +
        ((size_t)((si + 2) * 96 + r) * GTS + (size_t)(qi + 2) * 96 + 2 * cp) * 2);
    S[r * 96 + 2 * cp]     = (blo(d0) + blo(d1)) + blo(d2);
    S[r * 96 + 2 * cp + 1] = (bhi(d0) + bhi(d1)) + bhi(d2);
  }
  if (t < 94) rnlds[t] = rnormS[si * 94 + t];
  __syncthreads();

  if (t < 752) {
    int g = t / 94, qj = t - g * 94;               // lane -> (sj-group, qj)
    int sj0 = g * 12;
    int niter = (g == 7) ? 10 : 12;                // sj 0..11, ..., 84..93
    float bv = -3.0e38f; int bs = sj0;
    int base = sj0 * 96 + qj;
    for (int j = 0; j < niter; ++j) {
      float t0 = S[base];                          // (sj,   qj)
      float t1 = S[base + 97];                     // (sj+1, qj+1)
      float t2 = S[base + 194];                    // (sj+2, qj+2)
      float v = ((t0 + t1) + t2) * rnlds[sj0 + j];
      if (v > bv) { bv = v; bs = sj0 + j; }
      base += 96;
    }
    int sidx = si * 94 + bs;
    sm[g][qj] = ((unsigned long long)ordf(bv) << 32) |
                (unsigned long long)(0xFFFFFFFFu - (unsigned)sidx);
  }
  __syncthreads();
  if (t < 94) {
    unsigned long long c = sm[0][t];
    #pragma unroll
    for (int r = 1; r < 8; ++r) {
      unsigned long long o = sm[r][t];
      if (o > c) c = o;                            // ties -> smaller s
    }
    atomicMax(best + (size_t)(qi * 94 + t) * 8, c);
  }
}

// ---------------------------------------------------------------------------
// 3c) Fallback: direct implicit-im2col GEMM+argmax (proven 265us path),
//     used when the workspace cannot hold GT.
// ---------------------------------------------------------------------------
__global__ __launch_bounds__(256, 2) void gemm_argmax_kernel(
    const unsigned char* __restrict__ TA, const unsigned char* __restrict__ TB,
    const float* __restrict__ rnormS, unsigned long long* __restrict__ best) {
  __shared__ unsigned char As[128 * 128];
  __shared__ unsigned char Bs[128 * 128];

  int orig = blockIdx.x;
  int xcd = orig & 7, idx = orig >> 3;
  int pid = (xcd < 4 ? xcd * 613 : 4 * 613 + (xcd - 4) * 612) + idx;

  int mt = pid % NTILE, nt = pid / NTILE;
  int q0 = mt * 128, s0 = nt * 128;
  int t = threadIdx.x, lane = t & 63, wave = t >> 6;
  int wm = wave >> 1, wn = wave & 1;

  int rr = t >> 3;
  int qc = (t & 7) ^ (rr & 7);
  const unsigned char* gA[4];
  const unsigned char* gB[4];
  #pragma unroll
  for (int i = 0; i < 4; ++i) {
    int qa = q0 + 32 * i + rr; if (qa > NP - 1) qa = NP - 1;
    int sa = s0 + 32 * i + rr; if (sa > NP - 1) sa = NP - 1;
    gA[i] = TA + (size_t)((qa / PW) * IW + (qa % PW)) * CH + qc * 16;
    gB[i] = TB + (size_t)((sa / PW) * IW + (sa % PW)) * CH + qc * 16;
  }
  unsigned char* lA = As + t * 16;
  unsigned char* lB = Bs + t * 16;

  f32x16 acc[2][2];
  #pragma unroll
  for (int mi = 0; mi < 2; ++mi)
    #pragma unroll
    for (int ni = 0; ni < 2; ++ni)
      #pragma unroll
      for (int j = 0; j < 16; ++j) acc[mi][ni][j] = 0.f;

  int kq = lane >> 5, sw = lane & 7;
  const unsigned char* Arow = As + (size_t)(wm * 64 + (lane & 31)) * 128;
  const unsigned char* Brow = Bs + (size_t)(wn * 64 + (lane & 31)) * 128;

  #pragma unroll 1
  for (int kt = 0; kt < KT2; ++kt) {
    int chunk = kt >> 1;
    int kh = chunk / 3, kw = chunk - kh * 3;
    int choff = (kh * IW + kw) * CH + (kt & 1) * 128;
    if (kt) __syncthreads();
    #pragma unroll
    for (int i = 0; i < 4; ++i) {
      gl16(gA[i] + choff, lA + i * 4096);
      gl16(gB[i] + choff, lB + i * 4096);
    }
    __syncthreads();
    #pragma unroll
    for (int h = 0; h < 2; ++h) {
      int c0 = 2 * kq + 4 * h;
      int o0 = (c0 ^ sw) * 16, o1 = ((c0 + 1) ^ sw) * 16;
      i32x8 af[2], bf[2];
      #pragma unroll
      for (int mi = 0; mi < 2; ++mi) af[mi] = ldfrag(Arow + mi * 32 * 128, o0, o1);
      #pragma unroll
      for (int ni = 0; ni < 2; ++ni) bf[ni] = ldfrag(Brow + ni * 32 * 128, o0, o1);
      #pragma unroll
      for (int mi = 0; mi < 2; ++mi)
        #pragma unroll
        for (int ni = 0; ni < 2; ++ni)
          acc[mi][ni] = __builtin_amdgcn_mfma_scale_f32_32x32x64_f8f6f4(
              af[mi], bf[ni], acc[mi][ni],
              0, 0, 0, 0x7F7F7F7F, 0, 0x7F7F7F7F);
    }
  }

  int col = lane & 31, half = lane >> 5;
  float rn[2]; int sc[2]; bool sv[2];
  #pragma unroll
  for (int ni = 0; ni < 2; ++ni) {
    int s = s0 + wn * 64 + ni * 32 + col;
    sc[ni] = s;
    sv[ni] = (s < NP);
    rn[ni] = sv[ni] ? rnormS[s] : 0.f;
  }
  #pragma unroll
  for (int mi = 0; mi < 2; ++mi) {
    #pragma unroll
    for (int reg = 0; reg < 16; ++reg) {
      unsigned long long p = 0ull;
      #pragma unroll
      for (int ni = 0; ni < 2; ++ni) {
        float v = acc[mi][ni][reg] * rn[ni];
        unsigned long long cand =
            ((unsigned long long)ordf(v) << 32) |
            (unsigned long long)(0xFFFFFFFFu - (unsigned)sc[ni]);
        cand = sv[ni] ? cand : 0ull;
        if (cand > p) p = cand;
      }
      #pragma unroll
      for (int sh = 16; sh >= 1; sh >>= 1) {
        unsigned long long o = __shfl_xor(p, sh, 64);
        if (o > p) p = o;
      }
      int q = q0 + wm * 64 + mi * 32 + (reg & 3) + 8 * (reg >> 2) + 4 * half;
      if (col == 0 && q < NP) atomicMax(best + (size_t)q * 8, p);
    }
  }
}

// ---------------------------------------------------------------------------
// 4) Final loss, parallel: 35 blocks, per-block partial sum, scaled atomicAdd.
// ---------------------------------------------------------------------------
__global__ __launch_bounds__(256) void finalize_kernel(
    const unsigned long long* __restrict__ best,
    const float* __restrict__ normS,
    const float* __restrict__ normsqS,
    const float* __restrict__ synsq,
    float* __restrict__ out) {
  __shared__ float swv[4];
  int t = threadIdx.x;
  int q = blockIdx.x * 256 + t;
  float a = 0.f;
  if (q < NP) {
    unsigned long long p = best[(size_t)q * 8];
    unsigned int o   = (unsigned int)(p >> 32);
    unsigned int idx = 0xFFFFFFFFu - (unsigned int)(p & 0xFFFFFFFFull);
    unsigned int u   = (o & 0x80000000u) ? (o & 0x7FFFFFFFu) : ~o;
    float resp = __uint_as_float(u);
    float dot  = resp * normS[idx];
    a = (synsq[q] - 2.f * dot + normsqS[idx]) * (1.f / ((float)NP * 2304.f));
  }
  #pragma unroll
  for (int m = 32; m >= 1; m >>= 1) a += __shfl_xor(a, m, 64);
  if ((t & 63) == 0) swv[t >> 6] = a;
  __syncthreads();
  if (t == 0) atomicAdd(out, (swv[0] + swv[1]) + (swv[2] + swv[3]));
}

// ---------------------------------------------------------------------------
extern "C" void kernel_launch(void* const* d_in, const int* in_sizes, int n_in,
                              void* d_out, int out_size, void* d_ws, size_t ws_size,
                              hipStream_t stream) {
  const float* inA = (const float*)d_in[0];  // input  (synthesis)
  const float* inB = (const float*)d_in[1];  // target (style)
  float* out = (float*)d_out;

  char* ws = (char*)d_ws;
  unsigned char* TA = (unsigned char*)ws;                 // 2,359,296 B fp8
  unsigned char* TB = (unsigned char*)(ws + 2359296);     // 2,359,296 B fp8
  float* rnormS  = (float*)(ws + 4718592);
  float* normS   = (float*)(ws + 4718592 + 35344);
  float* normsqS = (float*)(ws + 4718592 + 70688);
  float* synsq   = (float*)(ws + 4718592 + 106032);
  unsigned long long* best = (unsigned long long*)(ws + 4718592 + 141376);
  // best padded: 64 B per q -> 565,504 B. GT (bf16 9216x9216) follows.
  const size_t GT_OFF = 4718592ull + 141376ull + 565504ull;   // 5,425,472
  unsigned short* GT = (unsigned short*)(ws + GT_OFF);
  const size_t NEED = GT_OFF + (size_t)NPIX * NPIX * 2;       // 175,294,784

  (void)hipMemsetAsync(best, 0, (size_t)NP * 64, stream);
  (void)hipMemsetAsync(out, 0, sizeof(float), stream);
  prep_kernel<<<dim3(1152), dim3(256), 0, stream>>>(inA, inB, (unsigned int*)TA, (unsigned int*)TB);
  norms_kernel<<<dim3((2 * NP + 3) / 4), dim3(256), 0, stream>>>(
      (const unsigned int*)TA, (const unsigned int*)TB, rnormS, normS, normsqS, synsq);
  if (ws_size >= NEED) {
    g_gemm_kernel<<<dim3(72 * 72), dim3(256), 0, stream>>>(TA, TB, GT);
    tapsum_kernel<<<dim3(NP), dim3(768), 0, stream>>>(GT, rnormS, best);
  } else {
    gemm_argmax_kernel<<<dim3(NWG), dim3(256), 0, stream>>>(TA, TB, rnormS, best);
  }
  finalize_kernel<<<dim3(35), dim3(256), 0, stream>>>(best, normS, normsqS, synsq, out);
}